// Round 19
// baseline (200.268 us; speedup 1.0000x reference)
//
#include <hip/hip_runtime.h>
#include <hip/hip_bf16.h>

#define NPTS 200000
#define INC  64
#define OUTC 128
#define KTAP 27
#define EPSV 1e-5f
#define BM   128
#define NSHADOW 32

typedef __attribute__((ext_vector_type(8))) short bf16x8;
typedef __attribute__((ext_vector_type(4))) float f32x4;

__device__ __forceinline__ unsigned short f2bf(float f) {
  unsigned int u = __float_as_uint(f);
  return (unsigned short)((u + 0x7FFFu + ((u >> 16) & 1u)) >> 16);
}

// Fragment-packed bf16 weight image, 16KB/tap (R9-verified layout):
// chunk id=(ct*2+kk)*64+lane holds w[kk*32+(lane>>4)*8+j][ct*16+(lane&15)], j=0..7
__global__ void prep_wfrag(const float* __restrict__ w, unsigned char* __restrict__ img) {
  int tap = blockIdx.x;
  const float* wk = w + tap * (INC * OUTC);
  for (int id = threadIdx.x; id < 1024; id += blockDim.x) {
    int lane = id & 63;
    int ck   = id >> 6;
    int ct   = ck >> 1, kk = ck & 1;
    int c    = ct * 16 + (lane & 15);
    int k0   = kk * 32 + (lane >> 4) * 8;
    ushort4 lo, hi;
    lo.x = f2bf(wk[(k0+0)*OUTC + c]); lo.y = f2bf(wk[(k0+1)*OUTC + c]);
    lo.z = f2bf(wk[(k0+2)*OUTC + c]); lo.w = f2bf(wk[(k0+3)*OUTC + c]);
    hi.x = f2bf(wk[(k0+4)*OUTC + c]); hi.y = f2bf(wk[(k0+5)*OUTC + c]);
    hi.z = f2bf(wk[(k0+6)*OUTC + c]); hi.w = f2bf(wk[(k0+7)*OUTC + c]);
    unsigned char* d = img + (size_t)tap * 16384 + (size_t)id * 16;
    *(ushort4*)d       = lo;
    *(ushort4*)(d + 8) = hi;
  }
}

// feats fp32 (N x 64) -> bf16 rows of 128B.
__global__ __launch_bounds__(256) void prep_feats(const float* __restrict__ f,
                                                  unsigned short* __restrict__ o) {
  size_t i = (size_t)blockIdx.x * 256 + threadIdx.x;
  float4 a = ((const float4*)f)[i * 2];
  float4 b = ((const float4*)f)[i * 2 + 1];
  ushort4 ha = make_ushort4(f2bf(a.x), f2bf(a.y), f2bf(a.z), f2bf(a.w));
  ushort4 hb = make_ushort4(f2bf(b.x), f2bf(b.y), f2bf(b.z), f2bf(b.w));
  ((ushort4*)o)[i * 2]     = ha;
  ((ushort4*)o)[i * 2 + 1] = hb;
}

__global__ __launch_bounds__(512, 4) void conv_main(
    const unsigned short* __restrict__ fbf,   // NPTS+1 rows; row NPTS is zeros
    const int*   __restrict__ nmap,
    const unsigned char* __restrict__ wimg,
    float* __restrict__ out,
    float* __restrict__ shadow)
{
  __shared__ __align__(16) unsigned char ldsB[4][16384];   // 64KB ring, 4 slots
  __shared__ int rdy_[4];    // tap id staged in slot (-1 init)
  __shared__ int done_[4];   // cumulative per-slot consumption count

  const int t    = threadIdx.x;
  const int lane = t & 63;
  const int w    = t >> 6;       // 0..7
  const int cg   = w & 1;        // col group (64 cols)
  const int rg   = w >> 1;       // row group (32 rows, wave-exclusive)
  const int n0   = blockIdx.x * BM;
  const int l15  = lane & 15;
  const int lg   = lane >> 4;

  f32x4 zv = {0.f, 0.f, 0.f, 0.f};
  f32x4 acc[2][4];
  #pragma unroll
  for (int i = 0; i < 2; ++i)
    #pragma unroll
    for (int j = 0; j < 4; ++j) acc[i][j] = zv;

  const int nr0 = n0 + rg * 32 + l15;
  const int nr1 = nr0 + 16;
  const bool ok0 = nr0 < NPTS, ok1 = nr1 < NPTS;
  const int nc0 = ok0 ? nr0 : (NPTS - 1);
  const int nc1 = ok1 ? nr1 : (NPTS - 1);

  const unsigned char* fbp = (const unsigned char*)fbf;
  auto gp = [&](int g, bool ok) -> const unsigned char* {
    int gc = (g >= 0) ? g : NPTS;
    gc = ok ? gc : NPTS;
    return fbp + (size_t)gc * 128 + lg * 16;
  };

  const unsigned bb = (unsigned)(cg * 8192 + lane * 16);

  auto compute = [&](int slot, bf16x8& A0, bf16x8& A1, bf16x8& A2, bf16x8& A3) {
    const unsigned char* bufR = &ldsB[0][0] + (size_t)slot * 16384;
    #pragma unroll
    for (int kk = 0; kk < 2; ++kk) {
      bf16x8 b0 = *(const bf16x8*)(bufR + bb + kk * 1024 + 0 * 2048);
      bf16x8 b1 = *(const bf16x8*)(bufR + bb + kk * 1024 + 1 * 2048);
      bf16x8 b2 = *(const bf16x8*)(bufR + bb + kk * 1024 + 2 * 2048);
      bf16x8 b3 = *(const bf16x8*)(bufR + bb + kk * 1024 + 3 * 2048);
      bf16x8 a0 = kk ? A1 : A0;
      bf16x8 a1 = kk ? A3 : A2;
      acc[0][0] = __builtin_amdgcn_mfma_f32_16x16x32_bf16(a0, b0, acc[0][0], 0, 0, 0);
      acc[0][1] = __builtin_amdgcn_mfma_f32_16x16x32_bf16(a0, b1, acc[0][1], 0, 0, 0);
      acc[0][2] = __builtin_amdgcn_mfma_f32_16x16x32_bf16(a0, b2, acc[0][2], 0, 0, 0);
      acc[0][3] = __builtin_amdgcn_mfma_f32_16x16x32_bf16(a0, b3, acc[0][3], 0, 0, 0);
      acc[1][0] = __builtin_amdgcn_mfma_f32_16x16x32_bf16(a1, b0, acc[1][0], 0, 0, 0);
      acc[1][1] = __builtin_amdgcn_mfma_f32_16x16x32_bf16(a1, b1, acc[1][1], 0, 0, 0);
      acc[1][2] = __builtin_amdgcn_mfma_f32_16x16x32_bf16(a1, b2, acc[1][2], 0, 0, 0);
      acc[1][3] = __builtin_amdgcn_mfma_f32_16x16x32_bf16(a1, b3, acc[1][3], 0, 0, 0);
    }
  };

  int kpw = w;   // this wave's next production tap (w, w+8, w+16, w+24)

  // producer duty (rotating) + consumer wait for tap kn; NO s_barrier.
  auto duty = [&](int kn) {
    if (kpw < KTAP && kpw <= kn + 3) {
      int ss = kpw & 3, g = kpw >> 2;
      while (*(volatile int*)&done_[ss] != 8 * g) __builtin_amdgcn_s_sleep(1);
      // stage 16KB solo: 16 x glds (dest = uniform base + lane*16)
      const unsigned char* src = wimg + (size_t)kpw * 16384 + (size_t)lane * 16;
      unsigned char* dst = &ldsB[ss][lane * 16];
      #pragma unroll
      for (int j = 0; j < 16; ++j)
        __builtin_amdgcn_global_load_lds(
            (const __attribute__((address_space(1))) void*)(src + j * 1024),
            (__attribute__((address_space(3))) void*)(dst + j * 1024), 16, 0, 0);
      asm volatile("s_waitcnt vmcnt(0)" ::: "memory");   // per-wave drain only
      if (lane == 0) *(volatile int*)&rdy_[ss] = kpw;
      kpw += 8;
    }
    while (*(volatile int*)&rdy_[kn & 3] != kn) __builtin_amdgcn_s_sleep(1);
    asm volatile("" ::: "memory");
    __builtin_amdgcn_sched_barrier(0);
  };
  auto consumed = [&](int kn) {
    asm volatile("s_waitcnt lgkmcnt(0)" ::: "memory");
    asm volatile("" ::: "memory");
    if (lane == 0) atomicAdd(&done_[kn & 3], 1);
  };

  // tap body, no sync: gathers A(kn+2), nmap(kn+4), compute, rotate.
  auto tap_body = [&](int kn,
                      bf16x8& A0, bf16x8& A1, bf16x8& A2, bf16x8& A3,
                      int& Q0, int& Q1) {
    const unsigned char* p0 = gp(Q0, ok0);
    const unsigned char* p1 = gp(Q1, ok1);
    bf16x8 nA0 = *(const bf16x8*)p0;
    bf16x8 nA1 = *(const bf16x8*)(p0 + 64);
    bf16x8 nA2 = *(const bf16x8*)p1;
    bf16x8 nA3 = *(const bf16x8*)(p1 + 64);
    int kq = (kn + 4 < KTAP) ? (kn + 4) : (KTAP - 1);
    int nQ0 = nmap[(size_t)kq * NPTS + nc0];
    int nQ1 = nmap[(size_t)kq * NPTS + nc1];
    __builtin_amdgcn_sched_barrier(0);
    compute(kn & 3, A0, A1, A2, A3);
    A0 = nA0; A1 = nA1; A2 = nA2; A3 = nA3;
    Q0 = nQ0; Q1 = nQ1;
  };

  // ---- prologue: flags init; idx taps 0..3; A(0), A(1) ----
  if (t < 4) { rdy_[t] = -1; done_[t] = 0; }

  int j00 = nmap[nc0],                     j01 = nmap[nc1];
  int j10 = nmap[(size_t)NPTS + nc0],      j11 = nmap[(size_t)NPTS + nc1];
  int q00 = nmap[(size_t)2 * NPTS + nc0],  q01 = nmap[(size_t)2 * NPTS + nc1];
  int q10 = nmap[(size_t)3 * NPTS + nc0],  q11 = nmap[(size_t)3 * NPTS + nc1];

  bf16x8 aC0, aC1, aC2, aC3;   // even taps
  bf16x8 aN0, aN1, aN2, aN3;   // odd taps
  { const unsigned char* p = gp(j00, ok0); aC0 = *(const bf16x8*)p; aC1 = *(const bf16x8*)(p + 64); }
  { const unsigned char* p = gp(j01, ok1); aC2 = *(const bf16x8*)p; aC3 = *(const bf16x8*)(p + 64); }
  { const unsigned char* p = gp(j10, ok0); aN0 = *(const bf16x8*)p; aN1 = *(const bf16x8*)(p + 64); }
  { const unsigned char* p = gp(j11, ok1); aN2 = *(const bf16x8*)p; aN3 = *(const bf16x8*)(p + 64); }

  __syncthreads();   // flags visible; the ONLY block barrier in the kernel

  // ---- main loop: async pipeline, waves drift within a 3-tap window ----
  #pragma unroll 1
  for (int kn = 0; kn < KTAP - 1; kn += 2) {
    duty(kn);
    tap_body(kn, aC0, aC1, aC2, aC3, q00, q01);
    consumed(kn);
    duty(kn + 1);
    tap_body(kn + 1, aN0, aN1, aN2, aN3, q10, q11);
    consumed(kn + 1);
  }
  duty(KTAP - 1);
  compute((KTAP - 1) & 3, aC0, aC1, aC2, aC3);   // tap 26

  // ---- epilogue: guarded stores + wave-reduced sums -> 32-shadow atomics ----
  float* mysh = shadow + (blockIdx.x & (NSHADOW - 1)) * 256;
  #pragma unroll
  for (int nf = 0; nf < 4; ++nf) {
    int c = cg * 64 + nf * 16 + l15;
    float s = 0.f, s2 = 0.f;
    #pragma unroll
    for (int rt = 0; rt < 2; ++rt) {
      #pragma unroll
      for (int r = 0; r < 4; ++r) {
        float v = acc[rt][nf][r];
        int n = n0 + rg * 32 + rt * 16 + lg * 4 + r;
        if (n < NPTS) {
          s += v; s2 += v * v;
          out[(size_t)n * OUTC + c] = v;
        }
      }
    }
    s  += __shfl_xor(s, 16);  s  += __shfl_xor(s, 32);
    s2 += __shfl_xor(s2, 16); s2 += __shfl_xor(s2, 32);
    if (lane < 16) {
      atomicAdd(&mysh[c], s);
      atomicAdd(&mysh[128 + c], s2);
    }
  }
}

__global__ void finalize_stats(const float* __restrict__ shadow,
                               const float* __restrict__ gamma,
                               const float* __restrict__ beta,
                               float* __restrict__ scale,
                               float* __restrict__ shift) {
  __shared__ float accs[256];
  int t = threadIdx.x;
  float s = 0.f;
  for (int b = 0; b < NSHADOW; ++b) s += shadow[b * 256 + t];
  accs[t] = s;
  __syncthreads();
  if (t < OUTC) {
    float mean = accs[t] * (1.0f / (float)NPTS);
    float var  = accs[128 + t] * (1.0f / (float)NPTS) - mean * mean;
    var = fmaxf(var, 0.f);
    float sc = gamma[t] * rsqrtf(var + EPSV);
    scale[t] = sc;
    shift[t] = beta[t] - mean * sc;
  }
}

__global__ __launch_bounds__(256) void norm_relu(float* __restrict__ out,
                                                 const float* __restrict__ scale,
                                                 const float* __restrict__ shift) {
  __shared__ float s_sc[OUTC], s_sh[OUTC];
  if (threadIdx.x < OUTC) {
    s_sc[threadIdx.x] = scale[threadIdx.x];
    s_sh[threadIdx.x] = shift[threadIdx.x];
  }
  __syncthreads();
  const long total = (long)NPTS * OUTC / 4;
  for (long i = (long)blockIdx.x * blockDim.x + threadIdx.x; i < total;
       i += (long)gridDim.x * blockDim.x) {
    float4 v = ((float4*)out)[i];
    int cb = (int)(i & 31) * 4;
    v.x = fmaxf(v.x * s_sc[cb + 0] + s_sh[cb + 0], 0.f);
    v.y = fmaxf(v.y * s_sc[cb + 1] + s_sh[cb + 1], 0.f);
    v.z = fmaxf(v.z * s_sc[cb + 2] + s_sh[cb + 2], 0.f);
    v.w = fmaxf(v.w * s_sc[cb + 3] + s_sh[cb + 3], 0.f);
    ((float4*)out)[i] = v;
  }
}

extern "C" void kernel_launch(void* const* d_in, const int* in_sizes, int n_in,
                              void* d_out, int out_size, void* d_ws, size_t ws_size,
                              hipStream_t stream) {
  (void)in_sizes; (void)n_in; (void)out_size; (void)ws_size;
  const float* feats  = (const float*)d_in[0];
  const float* weight = (const float*)d_in[1];
  const float* gamma  = (const float*)d_in[2];
  const float* beta   = (const float*)d_in[3];
  const int*   nmap   = (const int*)d_in[4];
  float* out = (float*)d_out;

  unsigned char* ws = (unsigned char*)d_ws;
  const size_t FBF_BYTES  = (size_t)(NPTS + 1) * 128;  // 25,600,128 (+ zero row)
  const size_t WIMG_BYTES = (size_t)KTAP * 16384;      // 442,368
  unsigned short* fbf = (unsigned short*)ws;
  unsigned char* wimg = ws + FBF_BYTES;
  float* shadow = (float*)(ws + FBF_BYTES + WIMG_BYTES);  // 32*256
  float* scale  = shadow + NSHADOW * 256;
  float* shift  = scale + 128;

  hipMemsetAsync(shadow, 0, NSHADOW * 256 * sizeof(float), stream);
  hipMemsetAsync(fbf + (size_t)NPTS * 64, 0, 128, stream);   // zero row
  prep_wfrag<<<KTAP, 256, 0, stream>>>(weight, wimg);
  prep_feats<<<6250, 256, 0, stream>>>(feats, fbf);
  int grid = (NPTS + BM - 1) / BM;  // 1563
  conv_main<<<grid, 512, 0, stream>>>(fbf, nmap, wimg, out, shadow);
  finalize_stats<<<1, 256, 0, stream>>>(shadow, gamma, beta, scale, shift);
  norm_relu<<<4096, 256, 0, stream>>>(out, scale, shift);
}

// Round 20
// 184.772 us; speedup vs baseline: 1.0839x; 1.0839x over previous
//
#include <hip/hip_runtime.h>
#include <hip/hip_bf16.h>

#define NPTS 200000
#define INC  64
#define OUTC 128
#define KTAP 27
#define EPSV 1e-5f
#define BM   128
#define NSHADOW 32

typedef __attribute__((ext_vector_type(8))) short bf16x8;
typedef __attribute__((ext_vector_type(4))) float f32x4;

__device__ __forceinline__ unsigned short f2bf(float f) {
  unsigned int u = __float_as_uint(f);
  return (unsigned short)((u + 0x7FFFu + ((u >> 16) & 1u)) >> 16);
}

// Fragment-packed bf16 weight image, 16KB/tap (R9-verified layout):
// chunk id=(ct*2+kk)*64+lane holds w[kk*32+(lane>>4)*8+j][ct*16+(lane&15)], j=0..7
__global__ void prep_wfrag(const float* __restrict__ w, unsigned char* __restrict__ img) {
  int tap = blockIdx.x;
  const float* wk = w + tap * (INC * OUTC);
  for (int id = threadIdx.x; id < 1024; id += blockDim.x) {
    int lane = id & 63;
    int ck   = id >> 6;
    int ct   = ck >> 1, kk = ck & 1;
    int c    = ct * 16 + (lane & 15);
    int k0   = kk * 32 + (lane >> 4) * 8;
    ushort4 lo, hi;
    lo.x = f2bf(wk[(k0+0)*OUTC + c]); lo.y = f2bf(wk[(k0+1)*OUTC + c]);
    lo.z = f2bf(wk[(k0+2)*OUTC + c]); lo.w = f2bf(wk[(k0+3)*OUTC + c]);
    hi.x = f2bf(wk[(k0+4)*OUTC + c]); hi.y = f2bf(wk[(k0+5)*OUTC + c]);
    hi.z = f2bf(wk[(k0+6)*OUTC + c]); hi.w = f2bf(wk[(k0+7)*OUTC + c]);
    unsigned char* d = img + (size_t)tap * 16384 + (size_t)id * 16;
    *(ushort4*)d       = lo;
    *(ushort4*)(d + 8) = hi;
  }
}

// feats fp32 (N x 64) -> bf16 rows of 128B.
__global__ __launch_bounds__(256) void prep_feats(const float* __restrict__ f,
                                                  unsigned short* __restrict__ o) {
  size_t i = (size_t)blockIdx.x * 256 + threadIdx.x;
  float4 a = ((const float4*)f)[i * 2];
  float4 b = ((const float4*)f)[i * 2 + 1];
  ushort4 ha = make_ushort4(f2bf(a.x), f2bf(a.y), f2bf(a.z), f2bf(a.w));
  ushort4 hb = make_ushort4(f2bf(b.x), f2bf(b.y), f2bf(b.z), f2bf(b.w));
  ((ushort4*)o)[i * 2]     = ha;
  ((ushort4*)o)[i * 2 + 1] = hb;
}

// FULL: block fully in-range (no guards). RAWBF: write bf16 raw to ws.
template<bool FULL, int RAWBF>
__global__ __launch_bounds__(512, 4) void conv_main(
    const unsigned short* __restrict__ fbf,   // NPTS+1 rows; row NPTS is zeros
    const int*   __restrict__ nmap,
    const unsigned char* __restrict__ wimg,
    float* __restrict__ outf,
    unsigned short* __restrict__ rawbf,
    float* __restrict__ shadow,
    int blk0)
{
  __shared__ __align__(16) unsigned char ldsB[4][16384];   // 64KB, 2 slot-pairs

  const int t    = threadIdx.x;
  const int lane = t & 63;
  const int w    = t >> 6;       // 0..7
  const int cg   = w & 1;        // col group (64 cols)
  const int rg   = w >> 1;       // row group (32 rows, wave-exclusive)
  const int n0   = (blk0 + blockIdx.x) * BM;
  const int l15  = lane & 15;
  const int lg   = lane >> 4;

  f32x4 zv = {0.f, 0.f, 0.f, 0.f};
  f32x4 acc[2][4];
  #pragma unroll
  for (int i = 0; i < 2; ++i)
    #pragma unroll
    for (int j = 0; j < 4; ++j) acc[i][j] = zv;

  const int nr0 = n0 + rg * 32 + l15;
  const int nr1 = nr0 + 16;
  const bool ok0 = FULL || (nr0 < NPTS);
  const bool ok1 = FULL || (nr1 < NPTS);
  const int nc0 = ok0 ? nr0 : (NPTS - 1);
  const int nc1 = ok1 ? nr1 : (NPTS - 1);

  const unsigned char* fbp = (const unsigned char*)fbf;
  auto gp = [&](int g, bool ok) -> const unsigned char* {
    int gc = (g >= 0) ? g : NPTS;
    gc = ok ? gc : NPTS;
    return fbp + (size_t)gc * 128 + lg * 16;
  };

  auto stage = [&](int k, int slot) {
    const unsigned char* src = wimg + (size_t)k * 16384 + (size_t)t * 16;
    __builtin_amdgcn_global_load_lds(
        (const __attribute__((address_space(1))) void*)src,
        (__attribute__((address_space(3))) void*)(&ldsB[slot][t * 16]), 16, 0, 0);
    __builtin_amdgcn_global_load_lds(
        (const __attribute__((address_space(1))) void*)(src + 8192),
        (__attribute__((address_space(3))) void*)(&ldsB[slot][t * 16 + 8192]), 16, 0, 0);
  };

  const unsigned bb = (unsigned)(cg * 8192 + lane * 16);

  auto compute = [&](int slot, bf16x8& A0, bf16x8& A1, bf16x8& A2, bf16x8& A3) {
    const unsigned char* bufR = ldsB[slot];
    #pragma unroll
    for (int kk = 0; kk < 2; ++kk) {
      bf16x8 b0 = *(const bf16x8*)(bufR + bb + kk * 1024 + 0 * 2048);
      bf16x8 b1 = *(const bf16x8*)(bufR + bb + kk * 1024 + 1 * 2048);
      bf16x8 b2 = *(const bf16x8*)(bufR + bb + kk * 1024 + 2 * 2048);
      bf16x8 b3 = *(const bf16x8*)(bufR + bb + kk * 1024 + 3 * 2048);
      bf16x8 a0 = kk ? A1 : A0;
      bf16x8 a1 = kk ? A3 : A2;
      acc[0][0] = __builtin_amdgcn_mfma_f32_16x16x32_bf16(a0, b0, acc[0][0], 0, 0, 0);
      acc[0][1] = __builtin_amdgcn_mfma_f32_16x16x32_bf16(a0, b1, acc[0][1], 0, 0, 0);
      acc[0][2] = __builtin_amdgcn_mfma_f32_16x16x32_bf16(a0, b2, acc[0][2], 0, 0, 0);
      acc[0][3] = __builtin_amdgcn_mfma_f32_16x16x32_bf16(a0, b3, acc[0][3], 0, 0, 0);
      acc[1][0] = __builtin_amdgcn_mfma_f32_16x16x32_bf16(a1, b0, acc[1][0], 0, 0, 0);
      acc[1][1] = __builtin_amdgcn_mfma_f32_16x16x32_bf16(a1, b1, acc[1][1], 0, 0, 0);
      acc[1][2] = __builtin_amdgcn_mfma_f32_16x16x32_bf16(a1, b2, acc[1][2], 0, 0, 0);
      acc[1][3] = __builtin_amdgcn_mfma_f32_16x16x32_bf16(a1, b3, acc[1][3], 0, 0, 0);
    }
  };

  auto tap_body = [&](int kn, int slot,
                      bf16x8& A0, bf16x8& A1, bf16x8& A2, bf16x8& A3,
                      int& Q0, int& Q1) {
    const unsigned char* p0 = gp(Q0, ok0);
    const unsigned char* p1 = gp(Q1, ok1);
    bf16x8 nA0 = *(const bf16x8*)p0;
    bf16x8 nA1 = *(const bf16x8*)(p0 + 64);
    bf16x8 nA2 = *(const bf16x8*)p1;
    bf16x8 nA3 = *(const bf16x8*)(p1 + 64);
    int kq = (kn + 4 < KTAP) ? (kn + 4) : (KTAP - 1);
    int nQ0 = nmap[(size_t)kq * NPTS + nc0];
    int nQ1 = nmap[(size_t)kq * NPTS + nc1];
    __builtin_amdgcn_sched_barrier(0);
    compute(slot, A0, A1, A2, A3);
    A0 = nA0; A1 = nA1; A2 = nA2; A3 = nA3;
    Q0 = nQ0; Q1 = nQ1;
  };

  // ---- prologue: idx taps 0..3; A(0), A(1); stage taps 0,1; ONE full drain ----
  int j00 = nmap[nc0],                     j01 = nmap[nc1];
  int j10 = nmap[(size_t)NPTS + nc0],      j11 = nmap[(size_t)NPTS + nc1];
  int q00 = nmap[(size_t)2 * NPTS + nc0],  q01 = nmap[(size_t)2 * NPTS + nc1];
  int q10 = nmap[(size_t)3 * NPTS + nc0],  q11 = nmap[(size_t)3 * NPTS + nc1];

  bf16x8 aC0, aC1, aC2, aC3;   // even taps
  bf16x8 aN0, aN1, aN2, aN3;   // odd taps
  { const unsigned char* p = gp(j00, ok0); aC0 = *(const bf16x8*)p; aC1 = *(const bf16x8*)(p + 64); }
  { const unsigned char* p = gp(j01, ok1); aC2 = *(const bf16x8*)p; aC3 = *(const bf16x8*)(p + 64); }
  { const unsigned char* p = gp(j10, ok0); aN0 = *(const bf16x8*)p; aN1 = *(const bf16x8*)(p + 64); }
  { const unsigned char* p = gp(j11, ok1); aN2 = *(const bf16x8*)p; aN3 = *(const bf16x8*)(p + 64); }

  stage(0, 0);
  stage(1, 1);
  asm volatile("s_waitcnt vmcnt(0)" ::: "memory");
  asm volatile("s_waitcnt lgkmcnt(0)" ::: "memory");
  __builtin_amdgcn_s_barrier();
  __builtin_amdgcn_sched_barrier(0);

  // ---- main loop: 13 groups of 2 taps; ONE rendezvous per group (R18) ----
  #pragma unroll 1
  for (int g = 0; g < 13; ++g) {
    const int kn = 2 * g;
    const int p  = g & 1;
    const int q  = p ^ 1;
    int s0 = (kn + 2 < KTAP) ? (kn + 2) : (KTAP - 1);
    int s1 = (kn + 3 < KTAP) ? (kn + 3) : (KTAP - 1);
    stage(s0, q * 2 + 0);
    stage(s1, q * 2 + 1);
    __builtin_amdgcn_sched_barrier(0);
    tap_body(kn,     p * 2 + 0, aC0, aC1, aC2, aC3, q00, q01);
    tap_body(kn + 1, p * 2 + 1, aN0, aN1, aN2, aN3, q10, q11);
    asm volatile("s_waitcnt vmcnt(12)" ::: "memory");
    asm volatile("s_waitcnt lgkmcnt(0)" ::: "memory");
    __builtin_amdgcn_s_barrier();
    __builtin_amdgcn_sched_barrier(0);
  }
  compute(2, aC0, aC1, aC2, aC3);   // tap 26 (staged by g=12)

  // ---- epilogue: raw store (bf16 or fp32) + wave-reduced sums -> shadows ----
  float* mysh = shadow + ((blk0 + blockIdx.x) & (NSHADOW - 1)) * 256;
  #pragma unroll
  for (int nf = 0; nf < 4; ++nf) {
    int c = cg * 64 + nf * 16 + l15;
    float s = 0.f, s2 = 0.f;
    #pragma unroll
    for (int rt = 0; rt < 2; ++rt) {
      #pragma unroll
      for (int r = 0; r < 4; ++r) {
        float v = acc[rt][nf][r];
        int n = n0 + rg * 32 + rt * 16 + lg * 4 + r;
        if (FULL || (n < NPTS)) {
          s += v; s2 += v * v;
          if (RAWBF) rawbf[(size_t)n * OUTC + c] = f2bf(v);
          else       outf[(size_t)n * OUTC + c] = v;
        }
      }
    }
    s  += __shfl_xor(s, 16);  s  += __shfl_xor(s, 32);
    s2 += __shfl_xor(s2, 16); s2 += __shfl_xor(s2, 32);
    if (lane < 16) {
      atomicAdd(&mysh[c], s);
      atomicAdd(&mysh[128 + c], s2);
    }
  }
}

__global__ void finalize_stats(const float* __restrict__ shadow,
                               const float* __restrict__ gamma,
                               const float* __restrict__ beta,
                               float* __restrict__ scale,
                               float* __restrict__ shift) {
  __shared__ float accs[256];
  int t = threadIdx.x;
  float s = 0.f;
  for (int b = 0; b < NSHADOW; ++b) s += shadow[b * 256 + t];
  accs[t] = s;
  __syncthreads();
  if (t < OUTC) {
    float mean = accs[t] * (1.0f / (float)NPTS);
    float var  = accs[128 + t] * (1.0f / (float)NPTS) - mean * mean;
    var = fmaxf(var, 0.f);
    float sc = gamma[t] * rsqrtf(var + EPSV);
    scale[t] = sc;
    shift[t] = beta[t] - mean * sc;
  }
}

template<int RAWBF>
__global__ __launch_bounds__(256) void norm_relu(
    float* __restrict__ out, const unsigned short* __restrict__ rawbf,
    const float* __restrict__ scale, const float* __restrict__ shift) {
  __shared__ float s_sc[OUTC], s_sh[OUTC];
  if (threadIdx.x < OUTC) {
    s_sc[threadIdx.x] = scale[threadIdx.x];
    s_sh[threadIdx.x] = shift[threadIdx.x];
  }
  __syncthreads();
  const long total = (long)NPTS * OUTC / 8;   // 3.2M chunks of 8 elems
  for (long i = (long)blockIdx.x * blockDim.x + threadIdx.x; i < total;
       i += (long)gridDim.x * blockDim.x) {
    int cb = (int)(i & 15) * 8;   // row = 16 chunks of 8
    float v[8];
    if (RAWBF) {
      uint4 rw = ((const uint4*)rawbf)[i];
      v[0] = __uint_as_float((rw.x & 0xFFFFu) << 16);
      v[1] = __uint_as_float(rw.x & 0xFFFF0000u);
      v[2] = __uint_as_float((rw.y & 0xFFFFu) << 16);
      v[3] = __uint_as_float(rw.y & 0xFFFF0000u);
      v[4] = __uint_as_float((rw.z & 0xFFFFu) << 16);
      v[5] = __uint_as_float(rw.z & 0xFFFF0000u);
      v[6] = __uint_as_float((rw.w & 0xFFFFu) << 16);
      v[7] = __uint_as_float(rw.w & 0xFFFF0000u);
    } else {
      float4 a = ((const float4*)out)[i * 2];
      float4 b = ((const float4*)out)[i * 2 + 1];
      v[0]=a.x; v[1]=a.y; v[2]=a.z; v[3]=a.w;
      v[4]=b.x; v[5]=b.y; v[6]=b.z; v[7]=b.w;
    }
    float4 o0, o1;
    o0.x = fmaxf(v[0] * s_sc[cb+0] + s_sh[cb+0], 0.f);
    o0.y = fmaxf(v[1] * s_sc[cb+1] + s_sh[cb+1], 0.f);
    o0.z = fmaxf(v[2] * s_sc[cb+2] + s_sh[cb+2], 0.f);
    o0.w = fmaxf(v[3] * s_sc[cb+3] + s_sh[cb+3], 0.f);
    o1.x = fmaxf(v[4] * s_sc[cb+4] + s_sh[cb+4], 0.f);
    o1.y = fmaxf(v[5] * s_sc[cb+5] + s_sh[cb+5], 0.f);
    o1.z = fmaxf(v[6] * s_sc[cb+6] + s_sh[cb+6], 0.f);
    o1.w = fmaxf(v[7] * s_sc[cb+7] + s_sh[cb+7], 0.f);
    ((float4*)out)[i * 2]     = o0;
    ((float4*)out)[i * 2 + 1] = o1;
  }
}

extern "C" void kernel_launch(void* const* d_in, const int* in_sizes, int n_in,
                              void* d_out, int out_size, void* d_ws, size_t ws_size,
                              hipStream_t stream) {
  (void)in_sizes; (void)n_in; (void)out_size;
  const float* feats  = (const float*)d_in[0];
  const float* weight = (const float*)d_in[1];
  const float* gamma  = (const float*)d_in[2];
  const float* beta   = (const float*)d_in[3];
  const int*   nmap   = (const int*)d_in[4];
  float* out = (float*)d_out;

  unsigned char* ws = (unsigned char*)d_ws;
  const size_t FBF_BYTES  = (size_t)(NPTS + 1) * 128;  // 25,600,128 (+ zero row)
  const size_t WIMG_BYTES = (size_t)KTAP * 16384;      // 442,368
  const size_t STAT_BYTES = (NSHADOW * 256 + 256) * sizeof(float);
  const size_t RAW_BYTES  = (size_t)NPTS * OUTC * 2;   // 51,200,000
  unsigned short* fbf = (unsigned short*)ws;
  unsigned char* wimg = ws + FBF_BYTES;
  float* shadow = (float*)(ws + FBF_BYTES + WIMG_BYTES);
  float* scale  = shadow + NSHADOW * 256;
  float* shift  = scale + 128;
  unsigned short* rawbf = (unsigned short*)(ws + FBF_BYTES + WIMG_BYTES + STAT_BYTES);
  bool use_raw = ws_size >= FBF_BYTES + WIMG_BYTES + STAT_BYTES + RAW_BYTES;

  hipMemsetAsync(shadow, 0, NSHADOW * 256 * sizeof(float), stream);
  hipMemsetAsync(fbf + (size_t)NPTS * 64, 0, 128, stream);   // zero row
  prep_wfrag<<<KTAP, 256, 0, stream>>>(weight, wimg);
  prep_feats<<<6250, 256, 0, stream>>>(feats, fbf);
  const int nfull = NPTS / BM;   // 1562 guard-free blocks + 1 tail
  if (use_raw) {
    conv_main<true, 1><<<nfull, 512, 0, stream>>>(fbf, nmap, wimg, out, rawbf, shadow, 0);
    conv_main<false, 1><<<1, 512, 0, stream>>>(fbf, nmap, wimg, out, rawbf, shadow, nfull);
    finalize_stats<<<1, 256, 0, stream>>>(shadow, gamma, beta, scale, shift);
    norm_relu<1><<<4096, 256, 0, stream>>>(out, rawbf, scale, shift);
  } else {
    conv_main<true, 0><<<nfull, 512, 0, stream>>>(fbf, nmap, wimg, out, rawbf, shadow, 0);
    conv_main<false, 0><<<1, 512, 0, stream>>>(fbf, nmap, wimg, out, rawbf, shadow, nfull);
    finalize_stats<<<1, 256, 0, stream>>>(shadow, gamma, beta, scale, shift);
    norm_relu<0><<<4096, 256, 0, stream>>>(out, rawbf, scale, shift);
  }
}

// Round 21
// 158.713 us; speedup vs baseline: 1.2618x; 1.1642x over previous
//
#include <hip/hip_runtime.h>
#include <hip/hip_bf16.h>

#define NPTS 200000
#define INC  64
#define OUTC 128
#define KTAP 27
#define EPSV 1e-5f
#define BM   128
#define NFULL (NPTS / BM)   // 1562 guard-free blocks; block 1562 is the tail
#define NSHADOW 32

typedef __attribute__((ext_vector_type(8))) short bf16x8;
typedef __attribute__((ext_vector_type(4))) float f32x4;

__device__ __forceinline__ unsigned short f2bf(float f) {
  unsigned int u = __float_as_uint(f);
  return (unsigned short)((u + 0x7FFFu + ((u >> 16) & 1u)) >> 16);
}

// Fragment-packed bf16 weight image, 16KB/tap (R9-verified layout):
// chunk id=(ct*2+kk)*64+lane holds w[kk*32+(lane>>4)*8+j][ct*16+(lane&15)], j=0..7
// Block 0 also zeroes the shadow accumulators (replaces a memset dispatch).
__global__ void prep_wfrag(const float* __restrict__ w, unsigned char* __restrict__ img,
                           float* __restrict__ shadow) {
  if (blockIdx.x == 0) {
    for (int i = threadIdx.x; i < NSHADOW * 256; i += 256) shadow[i] = 0.f;
  }
  int tap = blockIdx.x;
  const float* wk = w + tap * (INC * OUTC);
  for (int id = threadIdx.x; id < 1024; id += blockDim.x) {
    int lane = id & 63;
    int ck   = id >> 6;
    int ct   = ck >> 1, kk = ck & 1;
    int c    = ct * 16 + (lane & 15);
    int k0   = kk * 32 + (lane >> 4) * 8;
    ushort4 lo, hi;
    lo.x = f2bf(wk[(k0+0)*OUTC + c]); lo.y = f2bf(wk[(k0+1)*OUTC + c]);
    lo.z = f2bf(wk[(k0+2)*OUTC + c]); lo.w = f2bf(wk[(k0+3)*OUTC + c]);
    hi.x = f2bf(wk[(k0+4)*OUTC + c]); hi.y = f2bf(wk[(k0+5)*OUTC + c]);
    hi.z = f2bf(wk[(k0+6)*OUTC + c]); hi.w = f2bf(wk[(k0+7)*OUTC + c]);
    unsigned char* d = img + (size_t)tap * 16384 + (size_t)id * 16;
    *(ushort4*)d       = lo;
    *(ushort4*)(d + 8) = hi;
  }
}

// feats fp32 (N x 64) -> bf16 rows of 128B. Block 6250 writes the zero row.
__global__ __launch_bounds__(256) void prep_feats(const float* __restrict__ f,
                                                  unsigned short* __restrict__ o) {
  size_t i = (size_t)blockIdx.x * 256 + threadIdx.x;
  if (i < (size_t)NPTS * 64 / 8) {
    float4 a = ((const float4*)f)[i * 2];
    float4 b = ((const float4*)f)[i * 2 + 1];
    ushort4 ha = make_ushort4(f2bf(a.x), f2bf(a.y), f2bf(a.z), f2bf(a.w));
    ushort4 hb = make_ushort4(f2bf(b.x), f2bf(b.y), f2bf(b.z), f2bf(b.w));
    ((ushort4*)o)[i * 2]     = ha;
    ((ushort4*)o)[i * 2 + 1] = hb;
  } else if (threadIdx.x < 8) {
    // zero row NPTS (128 bytes): 8 threads x 16B
    ((uint4*)(o + (size_t)NPTS * 64))[threadIdx.x] = make_uint4(0, 0, 0, 0);
  }
}

// R18 counted-vmcnt 2-tap-group structure (measured optimum).
template<bool FULL, int RAWBF>
__device__ __forceinline__ void conv_body(
    const unsigned short* __restrict__ fbf,
    const int*   __restrict__ nmap,
    const unsigned char* __restrict__ wimg,
    float* __restrict__ outf,
    unsigned short* __restrict__ rawbf,
    float* __restrict__ shadow,
    unsigned char (*ldsB)[16384])
{
  const int t    = threadIdx.x;
  const int lane = t & 63;
  const int w    = t >> 6;       // 0..7
  const int cg   = w & 1;        // col group (64 cols)
  const int rg   = w >> 1;       // row group (32 rows, wave-exclusive)
  const int n0   = blockIdx.x * BM;
  const int l15  = lane & 15;
  const int lg   = lane >> 4;

  f32x4 zv = {0.f, 0.f, 0.f, 0.f};
  f32x4 acc[2][4];
  #pragma unroll
  for (int i = 0; i < 2; ++i)
    #pragma unroll
    for (int j = 0; j < 4; ++j) acc[i][j] = zv;

  const int nr0 = n0 + rg * 32 + l15;
  const int nr1 = nr0 + 16;
  const bool ok0 = FULL || (nr0 < NPTS);
  const bool ok1 = FULL || (nr1 < NPTS);
  const int nc0 = ok0 ? nr0 : (NPTS - 1);
  const int nc1 = ok1 ? nr1 : (NPTS - 1);

  const unsigned char* fbp = (const unsigned char*)fbf;
  auto gp = [&](int g, bool ok) -> const unsigned char* {
    int gc = (g >= 0) ? g : NPTS;
    gc = ok ? gc : NPTS;
    return fbp + (size_t)gc * 128 + lg * 16;
  };

  auto stage = [&](int k, int slot) {
    const unsigned char* src = wimg + (size_t)k * 16384 + (size_t)t * 16;
    __builtin_amdgcn_global_load_lds(
        (const __attribute__((address_space(1))) void*)src,
        (__attribute__((address_space(3))) void*)(&ldsB[slot][t * 16]), 16, 0, 0);
    __builtin_amdgcn_global_load_lds(
        (const __attribute__((address_space(1))) void*)(src + 8192),
        (__attribute__((address_space(3))) void*)(&ldsB[slot][t * 16 + 8192]), 16, 0, 0);
  };

  const unsigned bb = (unsigned)(cg * 8192 + lane * 16);

  auto compute = [&](int slot, bf16x8& A0, bf16x8& A1, bf16x8& A2, bf16x8& A3) {
    const unsigned char* bufR = ldsB[slot];
    #pragma unroll
    for (int kk = 0; kk < 2; ++kk) {
      bf16x8 b0 = *(const bf16x8*)(bufR + bb + kk * 1024 + 0 * 2048);
      bf16x8 b1 = *(const bf16x8*)(bufR + bb + kk * 1024 + 1 * 2048);
      bf16x8 b2 = *(const bf16x8*)(bufR + bb + kk * 1024 + 2 * 2048);
      bf16x8 b3 = *(const bf16x8*)(bufR + bb + kk * 1024 + 3 * 2048);
      bf16x8 a0 = kk ? A1 : A0;
      bf16x8 a1 = kk ? A3 : A2;
      acc[0][0] = __builtin_amdgcn_mfma_f32_16x16x32_bf16(a0, b0, acc[0][0], 0, 0, 0);
      acc[0][1] = __builtin_amdgcn_mfma_f32_16x16x32_bf16(a0, b1, acc[0][1], 0, 0, 0);
      acc[0][2] = __builtin_amdgcn_mfma_f32_16x16x32_bf16(a0, b2, acc[0][2], 0, 0, 0);
      acc[0][3] = __builtin_amdgcn_mfma_f32_16x16x32_bf16(a0, b3, acc[0][3], 0, 0, 0);
      acc[1][0] = __builtin_amdgcn_mfma_f32_16x16x32_bf16(a1, b0, acc[1][0], 0, 0, 0);
      acc[1][1] = __builtin_amdgcn_mfma_f32_16x16x32_bf16(a1, b1, acc[1][1], 0, 0, 0);
      acc[1][2] = __builtin_amdgcn_mfma_f32_16x16x32_bf16(a1, b2, acc[1][2], 0, 0, 0);
      acc[1][3] = __builtin_amdgcn_mfma_f32_16x16x32_bf16(a1, b3, acc[1][3], 0, 0, 0);
    }
  };

  auto tap_body = [&](int kn, int slot,
                      bf16x8& A0, bf16x8& A1, bf16x8& A2, bf16x8& A3,
                      int& Q0, int& Q1) {
    const unsigned char* p0 = gp(Q0, ok0);
    const unsigned char* p1 = gp(Q1, ok1);
    bf16x8 nA0 = *(const bf16x8*)p0;
    bf16x8 nA1 = *(const bf16x8*)(p0 + 64);
    bf16x8 nA2 = *(const bf16x8*)p1;
    bf16x8 nA3 = *(const bf16x8*)(p1 + 64);
    int kq = (kn + 4 < KTAP) ? (kn + 4) : (KTAP - 1);
    int nQ0 = nmap[(size_t)kq * NPTS + nc0];
    int nQ1 = nmap[(size_t)kq * NPTS + nc1];
    __builtin_amdgcn_sched_barrier(0);
    compute(slot, A0, A1, A2, A3);
    A0 = nA0; A1 = nA1; A2 = nA2; A3 = nA3;
    Q0 = nQ0; Q1 = nQ1;
  };

  // ---- prologue ----
  int j00 = nmap[nc0],                     j01 = nmap[nc1];
  int j10 = nmap[(size_t)NPTS + nc0],      j11 = nmap[(size_t)NPTS + nc1];
  int q00 = nmap[(size_t)2 * NPTS + nc0],  q01 = nmap[(size_t)2 * NPTS + nc1];
  int q10 = nmap[(size_t)3 * NPTS + nc0],  q11 = nmap[(size_t)3 * NPTS + nc1];

  bf16x8 aC0, aC1, aC2, aC3;
  bf16x8 aN0, aN1, aN2, aN3;
  { const unsigned char* p = gp(j00, ok0); aC0 = *(const bf16x8*)p; aC1 = *(const bf16x8*)(p + 64); }
  { const unsigned char* p = gp(j01, ok1); aC2 = *(const bf16x8*)p; aC3 = *(const bf16x8*)(p + 64); }
  { const unsigned char* p = gp(j10, ok0); aN0 = *(const bf16x8*)p; aN1 = *(const bf16x8*)(p + 64); }
  { const unsigned char* p = gp(j11, ok1); aN2 = *(const bf16x8*)p; aN3 = *(const bf16x8*)(p + 64); }

  stage(0, 0);
  stage(1, 1);
  asm volatile("s_waitcnt vmcnt(0)" ::: "memory");
  asm volatile("s_waitcnt lgkmcnt(0)" ::: "memory");
  __builtin_amdgcn_s_barrier();
  __builtin_amdgcn_sched_barrier(0);

  // ---- 13 groups of 2 taps; one counted rendezvous per group ----
  #pragma unroll 1
  for (int g = 0; g < 13; ++g) {
    const int kn = 2 * g;
    const int p  = g & 1;
    const int q  = p ^ 1;
    int s0 = (kn + 2 < KTAP) ? (kn + 2) : (KTAP - 1);
    int s1 = (kn + 3 < KTAP) ? (kn + 3) : (KTAP - 1);
    stage(s0, q * 2 + 0);
    stage(s1, q * 2 + 1);
    __builtin_amdgcn_sched_barrier(0);
    tap_body(kn,     p * 2 + 0, aC0, aC1, aC2, aC3, q00, q01);
    tap_body(kn + 1, p * 2 + 1, aN0, aN1, aN2, aN3, q10, q11);
    asm volatile("s_waitcnt vmcnt(12)" ::: "memory");
    asm volatile("s_waitcnt lgkmcnt(0)" ::: "memory");
    __builtin_amdgcn_s_barrier();
    __builtin_amdgcn_sched_barrier(0);
  }
  compute(2, aC0, aC1, aC2, aC3);   // tap 26 (staged by g=12)

  // ---- epilogue: raw store + wave-reduced sums -> shadow atomics ----
  float* mysh = shadow + (blockIdx.x & (NSHADOW - 1)) * 256;
  #pragma unroll
  for (int nf = 0; nf < 4; ++nf) {
    int c = cg * 64 + nf * 16 + l15;
    float s = 0.f, s2 = 0.f;
    #pragma unroll
    for (int rt = 0; rt < 2; ++rt) {
      #pragma unroll
      for (int r = 0; r < 4; ++r) {
        float v = acc[rt][nf][r];
        int n = n0 + rg * 32 + rt * 16 + lg * 4 + r;
        if (FULL || (n < NPTS)) {
          s += v; s2 += v * v;
          if (RAWBF) rawbf[(size_t)n * OUTC + c] = f2bf(v);
          else       outf[(size_t)n * OUTC + c] = v;
        }
      }
    }
    s  += __shfl_xor(s, 16);  s  += __shfl_xor(s, 32);
    s2 += __shfl_xor(s2, 16); s2 += __shfl_xor(s2, 32);
    if (lane < 16) {
      atomicAdd(&mysh[c], s);
      atomicAdd(&mysh[128 + c], s2);
    }
  }
}

template<int RAWBF>
__global__ __launch_bounds__(512, 4) void conv_main(
    const unsigned short* __restrict__ fbf,
    const int*   __restrict__ nmap,
    const unsigned char* __restrict__ wimg,
    float* __restrict__ outf,
    unsigned short* __restrict__ rawbf,
    float* __restrict__ shadow)
{
  __shared__ __align__(16) unsigned char ldsB[4][16384];   // 64KB
  if ((int)blockIdx.x < NFULL)
    conv_body<true,  RAWBF>(fbf, nmap, wimg, outf, rawbf, shadow, ldsB);
  else
    conv_body<false, RAWBF>(fbf, nmap, wimg, outf, rawbf, shadow, ldsB);
}

__global__ void finalize_stats(const float* __restrict__ shadow,
                               const float* __restrict__ gamma,
                               const float* __restrict__ beta,
                               float* __restrict__ scale,
                               float* __restrict__ shift) {
  __shared__ float accs[256];
  int t = threadIdx.x;
  float s = 0.f;
  for (int b = 0; b < NSHADOW; ++b) s += shadow[b * 256 + t];
  accs[t] = s;
  __syncthreads();
  if (t < OUTC) {
    float mean = accs[t] * (1.0f / (float)NPTS);
    float var  = accs[128 + t] * (1.0f / (float)NPTS) - mean * mean;
    var = fmaxf(var, 0.f);
    float sc = gamma[t] * rsqrtf(var + EPSV);
    scale[t] = sc;
    shift[t] = beta[t] - mean * sc;
  }
}

template<int RAWBF>
__global__ __launch_bounds__(256) void norm_relu(
    float* __restrict__ out, const unsigned short* __restrict__ rawbf,
    const float* __restrict__ scale, const float* __restrict__ shift) {
  __shared__ float s_sc[OUTC], s_sh[OUTC];
  if (threadIdx.x < OUTC) {
    s_sc[threadIdx.x] = scale[threadIdx.x];
    s_sh[threadIdx.x] = shift[threadIdx.x];
  }
  __syncthreads();
  const long total = (long)NPTS * OUTC / 8;
  for (long i = (long)blockIdx.x * blockDim.x + threadIdx.x; i < total;
       i += (long)gridDim.x * blockDim.x) {
    int cb = (int)(i & 15) * 8;
    float v[8];
    if (RAWBF) {
      uint4 rw = ((const uint4*)rawbf)[i];
      v[0] = __uint_as_float((rw.x & 0xFFFFu) << 16);
      v[1] = __uint_as_float(rw.x & 0xFFFF0000u);
      v[2] = __uint_as_float((rw.y & 0xFFFFu) << 16);
      v[3] = __uint_as_float(rw.y & 0xFFFF0000u);
      v[4] = __uint_as_float((rw.z & 0xFFFFu) << 16);
      v[5] = __uint_as_float(rw.z & 0xFFFF0000u);
      v[6] = __uint_as_float((rw.w & 0xFFFFu) << 16);
      v[7] = __uint_as_float(rw.w & 0xFFFF0000u);
    } else {
      float4 a = ((const float4*)out)[i * 2];
      float4 b = ((const float4*)out)[i * 2 + 1];
      v[0]=a.x; v[1]=a.y; v[2]=a.z; v[3]=a.w;
      v[4]=b.x; v[5]=b.y; v[6]=b.z; v[7]=b.w;
    }
    float4 o0, o1;
    o0.x = fmaxf(v[0] * s_sc[cb+0] + s_sh[cb+0], 0.f);
    o0.y = fmaxf(v[1] * s_sc[cb+1] + s_sh[cb+1], 0.f);
    o0.z = fmaxf(v[2] * s_sc[cb+2] + s_sh[cb+2], 0.f);
    o0.w = fmaxf(v[3] * s_sc[cb+3] + s_sh[cb+3], 0.f);
    o1.x = fmaxf(v[4] * s_sc[cb+4] + s_sh[cb+4], 0.f);
    o1.y = fmaxf(v[5] * s_sc[cb+5] + s_sh[cb+5], 0.f);
    o1.z = fmaxf(v[6] * s_sc[cb+6] + s_sh[cb+6], 0.f);
    o1.w = fmaxf(v[7] * s_sc[cb+7] + s_sh[cb+7], 0.f);
    ((float4*)out)[i * 2]     = o0;
    ((float4*)out)[i * 2 + 1] = o1;
  }
}

extern "C" void kernel_launch(void* const* d_in, const int* in_sizes, int n_in,
                              void* d_out, int out_size, void* d_ws, size_t ws_size,
                              hipStream_t stream) {
  (void)in_sizes; (void)n_in; (void)out_size;
  const float* feats  = (const float*)d_in[0];
  const float* weight = (const float*)d_in[1];
  const float* gamma  = (const float*)d_in[2];
  const float* beta   = (const float*)d_in[3];
  const int*   nmap   = (const int*)d_in[4];
  float* out = (float*)d_out;

  unsigned char* ws = (unsigned char*)d_ws;
  const size_t FBF_BYTES  = (size_t)(NPTS + 1) * 128;  // 25,600,128 (+ zero row)
  const size_t WIMG_BYTES = (size_t)KTAP * 16384;      // 442,368
  const size_t STAT_BYTES = (NSHADOW * 256 + 256) * sizeof(float);
  const size_t RAW_BYTES  = (size_t)NPTS * OUTC * 2;   // 51,200,000
  unsigned short* fbf = (unsigned short*)ws;
  unsigned char* wimg = ws + FBF_BYTES;
  float* shadow = (float*)(ws + FBF_BYTES + WIMG_BYTES);
  float* scale  = shadow + NSHADOW * 256;
  float* shift  = scale + 128;
  unsigned short* rawbf = (unsigned short*)(ws + FBF_BYTES + WIMG_BYTES + STAT_BYTES);
  bool use_raw = ws_size >= FBF_BYTES + WIMG_BYTES + STAT_BYTES + RAW_BYTES;

  prep_wfrag<<<KTAP, 256, 0, stream>>>(weight, wimg, shadow);
  prep_feats<<<6251, 256, 0, stream>>>(feats, fbf);
  if (use_raw) {
    conv_main<1><<<NFULL + 1, 512, 0, stream>>>(fbf, nmap, wimg, out, rawbf, shadow);
    finalize_stats<<<1, 256, 0, stream>>>(shadow, gamma, beta, scale, shift);
    norm_relu<1><<<4096, 256, 0, stream>>>(out, rawbf, scale, shift);
  } else {
    conv_main<0><<<NFULL + 1, 512, 0, stream>>>(fbf, nmap, wimg, out, rawbf, shadow);
    finalize_stats<<<1, 256, 0, stream>>>(shadow, gamma, beta, scale, shift);
    norm_relu<0><<<4096, 256, 0, stream>>>(out, rawbf, scale, shift);
  }
}

// Round 22
// 150.552 us; speedup vs baseline: 1.3302x; 1.0542x over previous
//
#include <hip/hip_runtime.h>
#include <hip/hip_bf16.h>

#define NPTS 200000
#define INC  64
#define OUTC 128
#define KTAP 27
#define EPSV 1e-5f
#define BM   128
#define NFULL (NPTS / BM)   // 1562 guard-free blocks; block 1562 is the tail
#define NSHADOW 32

typedef __attribute__((ext_vector_type(8))) short bf16x8;
typedef __attribute__((ext_vector_type(4))) float f32x4;

__device__ __forceinline__ unsigned short f2bf(float f) {
  unsigned int u = __float_as_uint(f);
  return (unsigned short)((u + 0x7FFFu + ((u >> 16) & 1u)) >> 16);
}

// Unified prep: blocks 0..26 build the fragment-packed weight image
// (block 0 also zeroes the shadow accumulators); blocks 27..6276 convert
// feats fp32 -> bf16 rows; block 6277 writes the zero row.
__global__ __launch_bounds__(256) void prep_all(
    const float* __restrict__ w, unsigned char* __restrict__ img,
    const float* __restrict__ f, unsigned short* __restrict__ o,
    float* __restrict__ shadow)
{
  int b = blockIdx.x;
  if (b < KTAP) {
    if (b == 0) {
      for (int i = threadIdx.x; i < NSHADOW * 256; i += 256) shadow[i] = 0.f;
    }
    const float* wk = w + b * (INC * OUTC);
    for (int id = threadIdx.x; id < 1024; id += blockDim.x) {
      int lane = id & 63;
      int ck   = id >> 6;
      int ct   = ck >> 1, kk = ck & 1;
      int c    = ct * 16 + (lane & 15);
      int k0   = kk * 32 + (lane >> 4) * 8;
      ushort4 lo, hi;
      lo.x = f2bf(wk[(k0+0)*OUTC + c]); lo.y = f2bf(wk[(k0+1)*OUTC + c]);
      lo.z = f2bf(wk[(k0+2)*OUTC + c]); lo.w = f2bf(wk[(k0+3)*OUTC + c]);
      hi.x = f2bf(wk[(k0+4)*OUTC + c]); hi.y = f2bf(wk[(k0+5)*OUTC + c]);
      hi.z = f2bf(wk[(k0+6)*OUTC + c]); hi.w = f2bf(wk[(k0+7)*OUTC + c]);
      unsigned char* d = img + (size_t)b * 16384 + (size_t)id * 16;
      *(ushort4*)d       = lo;
      *(ushort4*)(d + 8) = hi;
    }
  } else {
    size_t i = (size_t)(b - KTAP) * 256 + threadIdx.x;
    if (i < (size_t)NPTS * 64 / 8) {
      float4 a = ((const float4*)f)[i * 2];
      float4 bb = ((const float4*)f)[i * 2 + 1];
      ushort4 ha = make_ushort4(f2bf(a.x), f2bf(a.y), f2bf(a.z), f2bf(a.w));
      ushort4 hb = make_ushort4(f2bf(bb.x), f2bf(bb.y), f2bf(bb.z), f2bf(bb.w));
      ((ushort4*)o)[i * 2]     = ha;
      ((ushort4*)o)[i * 2 + 1] = hb;
    } else if (threadIdx.x < 8) {
      ((uint4*)(o + (size_t)NPTS * 64))[threadIdx.x] = make_uint4(0, 0, 0, 0);
    }
  }
}

// R18 counted-vmcnt 2-tap-group structure (measured optimum) — unchanged.
template<bool FULL, int RAWBF>
__device__ __forceinline__ void conv_body(
    const unsigned short* __restrict__ fbf,
    const int*   __restrict__ nmap,
    const unsigned char* __restrict__ wimg,
    float* __restrict__ outf,
    unsigned short* __restrict__ rawbf,
    float* __restrict__ shadow,
    unsigned char (*ldsB)[16384])
{
  const int t    = threadIdx.x;
  const int lane = t & 63;
  const int w    = t >> 6;       // 0..7
  const int cg   = w & 1;        // col group (64 cols)
  const int rg   = w >> 1;       // row group (32 rows, wave-exclusive)
  const int n0   = blockIdx.x * BM;
  const int l15  = lane & 15;
  const int lg   = lane >> 4;

  f32x4 zv = {0.f, 0.f, 0.f, 0.f};
  f32x4 acc[2][4];
  #pragma unroll
  for (int i = 0; i < 2; ++i)
    #pragma unroll
    for (int j = 0; j < 4; ++j) acc[i][j] = zv;

  const int nr0 = n0 + rg * 32 + l15;
  const int nr1 = nr0 + 16;
  const bool ok0 = FULL || (nr0 < NPTS);
  const bool ok1 = FULL || (nr1 < NPTS);
  const int nc0 = ok0 ? nr0 : (NPTS - 1);
  const int nc1 = ok1 ? nr1 : (NPTS - 1);

  const unsigned char* fbp = (const unsigned char*)fbf;
  auto gp = [&](int g, bool ok) -> const unsigned char* {
    int gc = (g >= 0) ? g : NPTS;
    gc = ok ? gc : NPTS;
    return fbp + (size_t)gc * 128 + lg * 16;
  };

  auto stage = [&](int k, int slot) {
    const unsigned char* src = wimg + (size_t)k * 16384 + (size_t)t * 16;
    __builtin_amdgcn_global_load_lds(
        (const __attribute__((address_space(1))) void*)src,
        (__attribute__((address_space(3))) void*)(&ldsB[slot][t * 16]), 16, 0, 0);
    __builtin_amdgcn_global_load_lds(
        (const __attribute__((address_space(1))) void*)(src + 8192),
        (__attribute__((address_space(3))) void*)(&ldsB[slot][t * 16 + 8192]), 16, 0, 0);
  };

  const unsigned bb = (unsigned)(cg * 8192 + lane * 16);

  auto compute = [&](int slot, bf16x8& A0, bf16x8& A1, bf16x8& A2, bf16x8& A3) {
    const unsigned char* bufR = ldsB[slot];
    #pragma unroll
    for (int kk = 0; kk < 2; ++kk) {
      bf16x8 b0 = *(const bf16x8*)(bufR + bb + kk * 1024 + 0 * 2048);
      bf16x8 b1 = *(const bf16x8*)(bufR + bb + kk * 1024 + 1 * 2048);
      bf16x8 b2 = *(const bf16x8*)(bufR + bb + kk * 1024 + 2 * 2048);
      bf16x8 b3 = *(const bf16x8*)(bufR + bb + kk * 1024 + 3 * 2048);
      bf16x8 a0 = kk ? A1 : A0;
      bf16x8 a1 = kk ? A3 : A2;
      acc[0][0] = __builtin_amdgcn_mfma_f32_16x16x32_bf16(a0, b0, acc[0][0], 0, 0, 0);
      acc[0][1] = __builtin_amdgcn_mfma_f32_16x16x32_bf16(a0, b1, acc[0][1], 0, 0, 0);
      acc[0][2] = __builtin_amdgcn_mfma_f32_16x16x32_bf16(a0, b2, acc[0][2], 0, 0, 0);
      acc[0][3] = __builtin_amdgcn_mfma_f32_16x16x32_bf16(a0, b3, acc[0][3], 0, 0, 0);
      acc[1][0] = __builtin_amdgcn_mfma_f32_16x16x32_bf16(a1, b0, acc[1][0], 0, 0, 0);
      acc[1][1] = __builtin_amdgcn_mfma_f32_16x16x32_bf16(a1, b1, acc[1][1], 0, 0, 0);
      acc[1][2] = __builtin_amdgcn_mfma_f32_16x16x32_bf16(a1, b2, acc[1][2], 0, 0, 0);
      acc[1][3] = __builtin_amdgcn_mfma_f32_16x16x32_bf16(a1, b3, acc[1][3], 0, 0, 0);
    }
  };

  auto tap_body = [&](int kn, int slot,
                      bf16x8& A0, bf16x8& A1, bf16x8& A2, bf16x8& A3,
                      int& Q0, int& Q1) {
    const unsigned char* p0 = gp(Q0, ok0);
    const unsigned char* p1 = gp(Q1, ok1);
    bf16x8 nA0 = *(const bf16x8*)p0;
    bf16x8 nA1 = *(const bf16x8*)(p0 + 64);
    bf16x8 nA2 = *(const bf16x8*)p1;
    bf16x8 nA3 = *(const bf16x8*)(p1 + 64);
    int kq = (kn + 4 < KTAP) ? (kn + 4) : (KTAP - 1);
    int nQ0 = nmap[(size_t)kq * NPTS + nc0];
    int nQ1 = nmap[(size_t)kq * NPTS + nc1];
    __builtin_amdgcn_sched_barrier(0);
    compute(slot, A0, A1, A2, A3);
    A0 = nA0; A1 = nA1; A2 = nA2; A3 = nA3;
    Q0 = nQ0; Q1 = nQ1;
  };

  // ---- prologue ----
  int j00 = nmap[nc0],                     j01 = nmap[nc1];
  int j10 = nmap[(size_t)NPTS + nc0],      j11 = nmap[(size_t)NPTS + nc1];
  int q00 = nmap[(size_t)2 * NPTS + nc0],  q01 = nmap[(size_t)2 * NPTS + nc1];
  int q10 = nmap[(size_t)3 * NPTS + nc0],  q11 = nmap[(size_t)3 * NPTS + nc1];

  bf16x8 aC0, aC1, aC2, aC3;
  bf16x8 aN0, aN1, aN2, aN3;
  { const unsigned char* p = gp(j00, ok0); aC0 = *(const bf16x8*)p; aC1 = *(const bf16x8*)(p + 64); }
  { const unsigned char* p = gp(j01, ok1); aC2 = *(const bf16x8*)p; aC3 = *(const bf16x8*)(p + 64); }
  { const unsigned char* p = gp(j10, ok0); aN0 = *(const bf16x8*)p; aN1 = *(const bf16x8*)(p + 64); }
  { const unsigned char* p = gp(j11, ok1); aN2 = *(const bf16x8*)p; aN3 = *(const bf16x8*)(p + 64); }

  stage(0, 0);
  stage(1, 1);
  asm volatile("s_waitcnt vmcnt(0)" ::: "memory");
  asm volatile("s_waitcnt lgkmcnt(0)" ::: "memory");
  __builtin_amdgcn_s_barrier();
  __builtin_amdgcn_sched_barrier(0);

  // ---- 13 groups of 2 taps; one counted rendezvous per group ----
  #pragma unroll 1
  for (int g = 0; g < 13; ++g) {
    const int kn = 2 * g;
    const int p  = g & 1;
    const int q  = p ^ 1;
    int s0 = (kn + 2 < KTAP) ? (kn + 2) : (KTAP - 1);
    int s1 = (kn + 3 < KTAP) ? (kn + 3) : (KTAP - 1);
    stage(s0, q * 2 + 0);
    stage(s1, q * 2 + 1);
    __builtin_amdgcn_sched_barrier(0);
    tap_body(kn,     p * 2 + 0, aC0, aC1, aC2, aC3, q00, q01);
    tap_body(kn + 1, p * 2 + 1, aN0, aN1, aN2, aN3, q10, q11);
    asm volatile("s_waitcnt vmcnt(12)" ::: "memory");
    asm volatile("s_waitcnt lgkmcnt(0)" ::: "memory");
    __builtin_amdgcn_s_barrier();
    __builtin_amdgcn_sched_barrier(0);
  }
  compute(2, aC0, aC1, aC2, aC3);   // tap 26 (staged by g=12)

  // ---- epilogue: raw store + wave-reduced sums -> shadow atomics ----
  float* mysh = shadow + (blockIdx.x & (NSHADOW - 1)) * 256;
  #pragma unroll
  for (int nf = 0; nf < 4; ++nf) {
    int c = cg * 64 + nf * 16 + l15;
    float s = 0.f, s2 = 0.f;
    #pragma unroll
    for (int rt = 0; rt < 2; ++rt) {
      #pragma unroll
      for (int r = 0; r < 4; ++r) {
        float v = acc[rt][nf][r];
        int n = n0 + rg * 32 + rt * 16 + lg * 4 + r;
        if (FULL || (n < NPTS)) {
          s += v; s2 += v * v;
          if (RAWBF) rawbf[(size_t)n * OUTC + c] = f2bf(v);
          else       outf[(size_t)n * OUTC + c] = v;
        }
      }
    }
    s  += __shfl_xor(s, 16);  s  += __shfl_xor(s, 32);
    s2 += __shfl_xor(s2, 16); s2 += __shfl_xor(s2, 32);
    if (lane < 16) {
      atomicAdd(&mysh[c], s);
      atomicAdd(&mysh[128 + c], s2);
    }
  }
}

template<int RAWBF>
__global__ __launch_bounds__(512, 4) void conv_main(
    const unsigned short* __restrict__ fbf,
    const int*   __restrict__ nmap,
    const unsigned char* __restrict__ wimg,
    float* __restrict__ outf,
    unsigned short* __restrict__ rawbf,
    float* __restrict__ shadow)
{
  __shared__ __align__(16) unsigned char ldsB[4][16384];   // 64KB
  if ((int)blockIdx.x < NFULL)
    conv_body<true,  RAWBF>(fbf, nmap, wimg, outf, rawbf, shadow, ldsB);
  else
    conv_body<false, RAWBF>(fbf, nmap, wimg, outf, rawbf, shadow, ldsB);
}

// Fused: per-block redundant stats finalize (shadow is L2-hot) + norm + ReLU.
template<int RAWBF>
__global__ __launch_bounds__(256) void norm_relu(
    float* __restrict__ out, const unsigned short* __restrict__ rawbf,
    const float* __restrict__ shadow,
    const float* __restrict__ gamma, const float* __restrict__ beta) {
  __shared__ float accs[256];
  __shared__ float s_sc[OUTC], s_sh[OUTC];
  {
    int tt = threadIdx.x;
    float s = 0.f;
    #pragma unroll
    for (int b = 0; b < NSHADOW; ++b) s += shadow[b * 256 + tt];
    accs[tt] = s;
    __syncthreads();
    if (tt < OUTC) {
      float mean = accs[tt] * (1.0f / (float)NPTS);
      float var  = accs[128 + tt] * (1.0f / (float)NPTS) - mean * mean;
      var = fmaxf(var, 0.f);
      float sc = gamma[tt] * rsqrtf(var + EPSV);
      s_sc[tt] = sc;
      s_sh[tt] = beta[tt] - mean * sc;
    }
    __syncthreads();
  }
  const long total = (long)NPTS * OUTC / 8;
  for (long i = (long)blockIdx.x * blockDim.x + threadIdx.x; i < total;
       i += (long)gridDim.x * blockDim.x) {
    int cb = (int)(i & 15) * 8;
    float v[8];
    if (RAWBF) {
      uint4 rw = ((const uint4*)rawbf)[i];
      v[0] = __uint_as_float((rw.x & 0xFFFFu) << 16);
      v[1] = __uint_as_float(rw.x & 0xFFFF0000u);
      v[2] = __uint_as_float((rw.y & 0xFFFFu) << 16);
      v[3] = __uint_as_float(rw.y & 0xFFFF0000u);
      v[4] = __uint_as_float((rw.z & 0xFFFFu) << 16);
      v[5] = __uint_as_float(rw.z & 0xFFFF0000u);
      v[6] = __uint_as_float((rw.w & 0xFFFFu) << 16);
      v[7] = __uint_as_float(rw.w & 0xFFFF0000u);
    } else {
      float4 a = ((const float4*)out)[i * 2];
      float4 b = ((const float4*)out)[i * 2 + 1];
      v[0]=a.x; v[1]=a.y; v[2]=a.z; v[3]=a.w;
      v[4]=b.x; v[5]=b.y; v[6]=b.z; v[7]=b.w;
    }
    float4 o0, o1;
    o0.x = fmaxf(v[0] * s_sc[cb+0] + s_sh[cb+0], 0.f);
    o0.y = fmaxf(v[1] * s_sc[cb+1] + s_sh[cb+1], 0.f);
    o0.z = fmaxf(v[2] * s_sc[cb+2] + s_sh[cb+2], 0.f);
    o0.w = fmaxf(v[3] * s_sc[cb+3] + s_sh[cb+3], 0.f);
    o1.x = fmaxf(v[4] * s_sc[cb+4] + s_sh[cb+4], 0.f);
    o1.y = fmaxf(v[5] * s_sc[cb+5] + s_sh[cb+5], 0.f);
    o1.z = fmaxf(v[6] * s_sc[cb+6] + s_sh[cb+6], 0.f);
    o1.w = fmaxf(v[7] * s_sc[cb+7] + s_sh[cb+7], 0.f);
    ((float4*)out)[i * 2]     = o0;
    ((float4*)out)[i * 2 + 1] = o1;
  }
}

extern "C" void kernel_launch(void* const* d_in, const int* in_sizes, int n_in,
                              void* d_out, int out_size, void* d_ws, size_t ws_size,
                              hipStream_t stream) {
  (void)in_sizes; (void)n_in; (void)out_size;
  const float* feats  = (const float*)d_in[0];
  const float* weight = (const float*)d_in[1];
  const float* gamma  = (const float*)d_in[2];
  const float* beta   = (const float*)d_in[3];
  const int*   nmap   = (const int*)d_in[4];
  float* out = (float*)d_out;

  unsigned char* ws = (unsigned char*)d_ws;
  const size_t FBF_BYTES  = (size_t)(NPTS + 1) * 128;  // 25,600,128 (+ zero row)
  const size_t WIMG_BYTES = (size_t)KTAP * 16384;      // 442,368
  const size_t STAT_BYTES = (NSHADOW * 256) * sizeof(float);
  const size_t RAW_BYTES  = (size_t)NPTS * OUTC * 2;   // 51,200,000
  unsigned short* fbf = (unsigned short*)ws;
  unsigned char* wimg = ws + FBF_BYTES;
  float* shadow = (float*)(ws + FBF_BYTES + WIMG_BYTES);
  unsigned short* rawbf = (unsigned short*)(ws + FBF_BYTES + WIMG_BYTES + STAT_BYTES);
  bool use_raw = ws_size >= FBF_BYTES + WIMG_BYTES + STAT_BYTES + RAW_BYTES;

  prep_all<<<KTAP + 6251, 256, 0, stream>>>(weight, wimg, feats, fbf, shadow);
  if (use_raw) {
    conv_main<1><<<NFULL + 1, 512, 0, stream>>>(fbf, nmap, wimg, out, rawbf, shadow);
    norm_relu<1><<<2048, 256, 0, stream>>>(out, rawbf, shadow, gamma, beta);
  } else {
    conv_main<0><<<NFULL + 1, 512, 0, stream>>>(fbf, nmap, wimg, out, rawbf, shadow);
    norm_relu<0><<<2048, 256, 0, stream>>>(out, rawbf, shadow, gamma, beta);
  }
}